// Round 23
// baseline (276.242 us; speedup 1.0000x reference)
//
#include <hip/hip_runtime.h>
#include <hip/hip_bf16.h>

// Swin WindowAttention. R23: two-kernel split (A: QKV GEMM -> ws; B: attention
// + out-proj at 3 blk/CU), fallback to the R22 fused champion if ws is small.
// Rationale: fused structure is latency-bound at 2 waves/SIMD because phase-1's
// 144-f32 acc pins per-wave registers; B without phase 1 has ~150-reg demand
// and genuinely fits (256,3) -> 3 blocks/CU (R3/R10/R11 failed at demand>=175).

typedef __attribute__((ext_vector_type(8))) short  bf8;
typedef __attribute__((ext_vector_type(4))) short  bf4;
typedef __attribute__((ext_vector_type(4))) float  f4;

#define L2E 1.4426950408889634f

union VU { unsigned u[2]; bf4 v; };

__device__ __forceinline__ short f2b(float f) {
  unsigned u = __builtin_bit_cast(unsigned, f);
  unsigned r = u + 0x7fffu + ((u >> 16) & 1u);
  return (short)(r >> 16);
}
__device__ __forceinline__ unsigned pk2(float lo, float hi) {
  unsigned short l = __builtin_bit_cast(unsigned short, __float2bfloat16(lo));
  unsigned short h = __builtin_bit_cast(unsigned short, __float2bfloat16(hi));
  return (unsigned)l | ((unsigned)h << 16);
}
__device__ __forceinline__ bf4 pkbf4(f4 v) {
  VU r; r.u[0] = pk2(v[0], v[1]); r.u[1] = pk2(v[2], v[3]);
  return r.v;
}
__device__ __forceinline__ float ex2(float x) {
#if __has_builtin(__builtin_amdgcn_exp2f)
  return __builtin_amdgcn_exp2f(x);
#else
  float r; asm("v_exp_f32 %0, %1" : "=v"(r) : "v"(x)); return r;
#endif
}
__device__ __forceinline__ f4 mfma16(bf4 a, bf4 b, f4 c) {
#if __has_builtin(__builtin_amdgcn_mfma_f32_16x16x16bf16_1k)
  return __builtin_amdgcn_mfma_f32_16x16x16bf16_1k(a, b, c, 0, 0, 0);
#else
  f4 d;
  asm("v_mfma_f32_16x16x16_bf16 %0, %1, %2, %3" : "=v"(d) : "v"(a), "v"(b), "v"(c));
  return d;
#endif
}

// ---- prep (unchanged from R22): Wt, Wpt, and comb/separate bias+mask tables.
__global__ void wa_prep(const float* __restrict__ Wq, const float* __restrict__ Wk,
                        const float* __restrict__ Wv, const float* __restrict__ Wp,
                        const float* __restrict__ btab, const int* __restrict__ ridx,
                        const float* __restrict__ mask, int comb,
                        short* __restrict__ wt, short* __restrict__ wpt,
                        float* __restrict__ biasF, float* __restrict__ maskF,
                        float* __restrict__ combF) {
  int id = blockIdx.x * 256 + threadIdx.x;
  const int NWT = 576 * 384, NWP = 384 * 192;
  const int NBS = 12 * 64 * 64, NMS = 64 * 64 * 64, NCB = 64 * 12 * 64 * 64;
  if (id < NWT) {
    int row = id / 384, k = id - row * 384;
    int kind = row / 192, cc = row - kind * 192;
    const float* W = (kind == 0) ? Wq : (kind == 1 ? Wk : Wv);
    float v = W[k * 192 + cc];
    if (kind == 0) v *= 0.25f * L2E;
    wt[id] = f2b(v);
    return;
  }
  id -= NWT;
  if (id < NWP) {
    int n = id / 192, k = id - n * 192;
    wpt[id] = f2b(Wp[k * 384 + n]);
    return;
  }
  id -= NWP;
  if (comb) {
    if (id < NCB) {
      int win = id / 49152, rem = id - win * 49152;
      int h = rem >> 12, r2 = rem & 4095;
      int n = r2 >> 6, cc = r2 & 63;
      int m = (cc & 3) * 16 + (cc >> 2);
      float v;
      if (n >= 49)      v = -14427.0f;
      else if (m >= 49) v = 0.0f;
      else              v = (btab[ridx[m * 49 + n] * 12 + h]
                             + mask[win * 2401 + m * 49 + n]) * L2E;
      combF[id] = v;
    }
  } else {
    if (id < NBS) {
      int h = id >> 12, rem = id & 4095;
      int n = rem >> 6, cc = rem & 63;
      int m = (cc & 3) * 16 + (cc >> 2);
      float v;
      if (n >= 49)      v = -14427.0f;
      else if (m >= 49) v = 0.0f;
      else              v = btab[ridx[m * 49 + n] * 12 + h] * L2E;
      biasF[id] = v;
    } else if ((id -= NBS) < NMS) {
      int win = id >> 12, rem = id & 4095;
      int n = rem >> 6, cc = rem & 63;
      int m = (cc & 3) * 16 + (cc >> 2);
      maskF[id] = (m < 49 && n < 49) ? mask[win * 2401 + m * 49 + n] * L2E : 0.f;
    }
  }
}

struct __align__(16) SmemA { short xs[64][392]; };          // 50176 B
struct __align__(16) SmemB { short qs[64][200]; short ks[64][200]; }; // 51200 B
struct __align__(16) Smem {                                  // fused fallback
  union U {
    short xs[64][392];
    struct QK { short qs[64][200]; short ks[64][200]; } qk;
  } u;
};

// ================= Kernel A: QKV GEMM -> ws (split path) =================
// qtg/ktg: [win][64 tok][192] bf16 token-major; vtg: [win][192 dim][64 tok].
__global__ __launch_bounds__(256, 2)
void wa_qkv(const float* __restrict__ x,
            const float* __restrict__ bq, const float* __restrict__ bk,
            const float* __restrict__ bv, const short* __restrict__ wt,
            short* __restrict__ qtg, short* __restrict__ ktg,
            short* __restrict__ vtg) {
  __shared__ SmemA sm;
  const int tid = threadIdx.x;
  const int w   = tid >> 6;
  const int lid = tid & 63;
  const int g   = lid >> 4;
  const int c   = lid & 15;
  const int blk = blockIdx.x;
  {
    const float* xw = x + (size_t)blk * 18816;
    f4 xv[18];
#pragma unroll
    for (int it = 0; it < 18; it++) {
      int i = tid + it * 256;
      xv[it] = *(const f4*)(xw + (i / 96) * 384 + (i % 96) * 4);
    }
    const int iT = tid + 18 * 256;
    f4 xt = {0.f, 0.f, 0.f, 0.f};
    if (iT < 4704) xt = *(const f4*)(xw + (iT / 96) * 384 + (iT % 96) * 4);
#pragma unroll
    for (int it = 0; it < 18; it++) {
      int i = tid + it * 256;
      *(bf4*)&sm.xs[i / 96][(i % 96) * 4] = pkbf4(xv[it]);
    }
    if (iT < 4704) *(bf4*)&sm.xs[iT / 96][(iT % 96) * 4] = pkbf4(xt);
    const bf8 zz = {0,0,0,0,0,0,0,0};
#pragma unroll
    for (int it = 0; it < 3; it++) {
      int i = tid + it * 256;
      if (i < 735) { int row = 49 + i / 49, c8 = (i % 49) * 8; *(bf8*)&sm.xs[row][c8] = zz; }
    }
  }
  __syncthreads();

  f4 acc[4][9];
#pragma unroll
  for (int mt = 0; mt < 4; mt++)
#pragma unroll
    for (int i = 0; i < 9; i++) acc[mt][i] = (f4){0.f, 0.f, 0.f, 0.f};
  int rowb[9];
#pragma unroll
  for (int i = 0; i < 9; i++) {
    int kind = i / 3, hh = 3 * w + i % 3;
    rowb[i] = (kind * 192 + hh * 16 + c) * 384;
  }
#pragma unroll 3
  for (int ks = 0; ks < 12; ks++) {
    const int k0 = ks * 32 + g * 8;
    bf8 a[4], b[9];
#pragma unroll
    for (int mt = 0; mt < 4; mt++) a[mt] = *(const bf8*)&sm.xs[mt * 16 + c][k0];
#pragma unroll
    for (int i = 0; i < 9; i++) b[i] = *(const bf8*)(wt + rowb[i] + k0);
#pragma unroll
    for (int mt = 0; mt < 4; mt++)
#pragma unroll
      for (int i = 0; i < 9; i++)
        acc[mt][i] = __builtin_amdgcn_mfma_f32_16x16x32_bf16(a[mt], b[i], acc[mt][i], 0, 0, 0);
  }

  const size_t wb = (size_t)blk * 12288;   // 64*192 per window
#pragma unroll
  for (int i = 0; i < 9; i++) {
    const int kind = i / 3;
    const int col = (3 * w + i % 3) * 16 + c;
    const float bb = (kind == 0) ? (0.25f * L2E) * bq[col] : (kind == 1 ? bk[col] : bv[col]);
#pragma unroll
    for (int mt = 0; mt < 4; mt++) {
      unsigned w0 = pk2(acc[mt][i][0] + bb, acc[mt][i][1] + bb);
      unsigned w1 = pk2(acc[mt][i][2] + bb, acc[mt][i][3] + bb);
      if (kind == 2) {
        VU vv; vv.u[0] = w0; vv.u[1] = w1;
        *(bf4*)&vtg[wb + (size_t)col * 64 + mt * 16 + g * 4] = vv.v;   // dim-major
      } else {
        short* dst = ((kind == 0) ? qtg : ktg) + wb;                   // token-major
        dst[(mt * 16 + g * 4 + 0) * 192 + col] = (short)(w0 & 0xFFFFu);
        dst[(mt * 16 + g * 4 + 1) * 192 + col] = (short)(w0 >> 16);
        dst[(mt * 16 + g * 4 + 2) * 192 + col] = (short)(w1 & 0xFFFFu);
        dst[(mt * 16 + g * 4 + 3) * 192 + col] = (short)(w1 >> 16);
      }
    }
  }
}

// ========== Kernel B: attention + out-proj, 3 blocks/CU (split path) ==========
__global__ __launch_bounds__(256, 3)
void wa_attn(const short* __restrict__ qtg, const short* __restrict__ ktg,
             const short* __restrict__ vtg, const short* __restrict__ wpt,
             const float* __restrict__ combF, const float* __restrict__ bp,
             float* __restrict__ out) {
  __shared__ SmemB sm;
  const int tid = threadIdx.x;
  const int w   = tid >> 6;
  const int lid = tid & 63;
  const int g   = lid >> 4;
  const int c   = lid & 15;
  const int blk = blockIdx.x;
  const size_t wb = (size_t)blk * 12288;
  const int cwin = (blk & 63) * 49152;

  // stage Q,K (token-major [64][192]) into padded LDS rows
#pragma unroll
  for (int it = 0; it < 6; it++) {
    int i = tid + it * 256;                 // 1536 bf8 chunks per tensor
    int row = i / 24, c8 = (i % 24) * 8;
    *(bf8*)&sm.qs[row][c8] = *(const bf8*)&qtg[wb + row * 192 + c8];
    *(bf8*)&sm.ks[row][c8] = *(const bf8*)&ktg[wb + row * 192 + c8];
  }
  __syncthreads();

  const f4 z4 = {0.f, 0.f, 0.f, 0.f};
#pragma unroll
  for (int t = 0; t < 3; t++) {
    const int h  = 3 * w + t;
    const int hb = h * 16;
    // V frags issued EARLY (HBM latency hides under QK^T + softmax)
    bf4 vf[4];
#pragma unroll
    for (int kt = 0; kt < 4; kt++)
      vf[kt] = *(const bf4*)&vtg[wb + (size_t)(hb + c) * 64 + kt * 16 + g * 4];
    bf4 afr[4], bfr[4];
#pragma unroll
    for (int nt = 0; nt < 4; nt++)
      afr[nt] = *(const bf4*)&sm.ks[nt * 16 + c][hb + g * 4];
#pragma unroll
    for (int mt = 0; mt < 4; mt++)
      bfr[mt] = *(const bf4*)&sm.qs[mt * 16 + c][hb + g * 4];
    f4 s[4][4];
#pragma unroll
    for (int nt = 0; nt < 4; nt++)
#pragma unroll
      for (int mt = 0; mt < 4; mt++)
        s[nt][mt] = mfma16(afr[nt], bfr[mt], z4);
    const float* cbH = combF + cwin + (h << 12);
#pragma unroll
    for (int nt = 0; nt < 4; nt++)
#pragma unroll
      for (int r = 0; r < 4; r++) {
        const int n = nt * 16 + g * 4 + r;
        f4 cb4 = *(const f4*)&cbH[n * 64 + c * 4];
#pragma unroll
        for (int mt = 0; mt < 4; mt++)
          s[nt][mt][r] += cb4[mt];
      }
    float rin[4];
#pragma unroll
    for (int mt = 0; mt < 4; mt++) {
      float sum = 0.f;
#pragma unroll
      for (int nt = 0; nt < 4; nt++)
#pragma unroll
        for (int r = 0; r < 4; r++) {
          float p = ex2(s[nt][mt][r]);
          s[nt][mt][r] = p;
          sum += p;
        }
      sum += __shfl_xor(sum, 16, 64);
      sum += __shfl_xor(sum, 32, 64);
      rin[mt] = 1.f / sum;
    }
    unsigned ppk[4][4][2];
#pragma unroll
    for (int nt = 0; nt < 4; nt++)
#pragma unroll
      for (int mt = 0; mt < 4; mt++) {
        ppk[nt][mt][0] = pk2(s[nt][mt][0], s[nt][mt][1]);
        ppk[nt][mt][1] = pk2(s[nt][mt][2], s[nt][mt][3]);
      }
    f4 o[4];
#pragma unroll
    for (int mt = 0; mt < 4; mt++) o[mt] = z4;
#pragma unroll
    for (int kt = 0; kt < 4; kt++) {
#pragma unroll
      for (int mt = 0; mt < 4; mt++) {
        VU pu; pu.u[0] = ppk[kt][mt][0]; pu.u[1] = ppk[kt][mt][1];
        o[mt] = mfma16(vf[kt], pu.v, o[mt]);
      }
    }
#pragma unroll
    for (int mt = 0; mt < 4; mt++) {
      f4 ov = o[mt] * rin[mt];
      *(bf4*)&sm.qs[mt * 16 + c][hb + g * 4] = pkbf4(ov);   // O into own head cols
    }
  }
  __syncthreads();

  // phase 3 in two jt-halves (acc3[3][4] keeps peak registers low)
  float* ow = out + (size_t)blk * 18816;
#pragma unroll 1
  for (int half = 0; half < 2; half++) {
    f4 acc3[3][4];
#pragma unroll
    for (int jt = 0; jt < 3; jt++)
#pragma unroll
      for (int mt = 0; mt < 4; mt++) acc3[jt][mt] = (f4){0.f, 0.f, 0.f, 0.f};
#pragma unroll 2
    for (int ks3 = 0; ks3 < 6; ks3++) {
      const int k0 = ks3 * 32 + g * 8;
      bf8 ao[4], wbr[3];
#pragma unroll
      for (int mt = 0; mt < 4; mt++) ao[mt] = *(const bf8*)&sm.qs[mt * 16 + c][k0];
#pragma unroll
      for (int jt = 0; jt < 3; jt++)
        wbr[jt] = *(const bf8*)(wpt + (w * 96 + half * 48 + jt * 16 + c) * 192 + k0);
#pragma unroll
      for (int jt = 0; jt < 3; jt++)
#pragma unroll
        for (int mt = 0; mt < 4; mt++)
          acc3[jt][mt] = __builtin_amdgcn_mfma_f32_16x16x32_bf16(wbr[jt], ao[mt], acc3[jt][mt], 0, 0, 0);
    }
#pragma unroll
    for (int jt = 0; jt < 3; jt++) {
      const int colb = w * 96 + half * 48 + jt * 16 + g * 4;
      const f4 bp4 = *(const f4*)&bp[colb];
#pragma unroll
      for (int mt = 0; mt < 4; mt++) {
        const int m = mt * 16 + c;
        if (m < 49) {
          f4 v = acc3[jt][mt] + bp4;
          *(f4*)&ow[m * 384 + colb] = v;
        }
      }
    }
  }
}

// ================= fused fallback (exact R22 champion) =================
template <bool COMB>
__global__ __launch_bounds__(256, 2)
void wa_main(const float* __restrict__ x,
             const float* __restrict__ bq, const float* __restrict__ bk,
             const float* __restrict__ bv, const float* __restrict__ bp,
             const short* __restrict__ wt, const short* __restrict__ wpt,
             const float* __restrict__ biasF, const float* __restrict__ maskF,
             const float* __restrict__ combF, float* __restrict__ out) {
  __shared__ Smem sm;
  const int tid = threadIdx.x;
  const int w   = tid >> 6;
  const int lid = tid & 63;
  const int g   = lid >> 4;
  const int c   = lid & 15;
  const int blk = blockIdx.x;
  const int mwin = (blk & 63) << 12;
  const int cwin = (blk & 63) * 49152;
  {
    const float* xw = x + (size_t)blk * 18816;
    f4 xv[18];
#pragma unroll
    for (int it = 0; it < 18; it++) {
      int i = tid + it * 256;
      xv[it] = *(const f4*)(xw + (i / 96) * 384 + (i % 96) * 4);
    }
    const int iT = tid + 18 * 256;
    f4 xt = {0.f, 0.f, 0.f, 0.f};
    if (iT < 4704) xt = *(const f4*)(xw + (iT / 96) * 384 + (iT % 96) * 4);
#pragma unroll
    for (int it = 0; it < 18; it++) {
      int i = tid + it * 256;
      *(bf4*)&sm.u.xs[i / 96][(i % 96) * 4] = pkbf4(xv[it]);
    }
    if (iT < 4704) *(bf4*)&sm.u.xs[iT / 96][(iT % 96) * 4] = pkbf4(xt);
    const bf8 zz = {0,0,0,0,0,0,0,0};
#pragma unroll
    for (int it = 0; it < 3; it++) {
      int i = tid + it * 256;
      if (i < 735) { int row = 49 + i / 49, c8 = (i % 49) * 8; *(bf8*)&sm.u.xs[row][c8] = zz; }
    }
  }
  __syncthreads();
  f4 acc[4][9];
#pragma unroll
  for (int mt = 0; mt < 4; mt++)
#pragma unroll
    for (int i = 0; i < 9; i++) acc[mt][i] = (f4){0.f, 0.f, 0.f, 0.f};
  int rowb[9];
#pragma unroll
  for (int i = 0; i < 9; i++) {
    int kind = i / 3, hh = 3 * w + i % 3;
    rowb[i] = (kind * 192 + hh * 16 + c) * 384;
  }
#pragma unroll 3
  for (int ks = 0; ks < 12; ks++) {
    const int k0 = ks * 32 + g * 8;
    bf8 a[4], b[9];
#pragma unroll
    for (int mt = 0; mt < 4; mt++) a[mt] = *(const bf8*)&sm.u.xs[mt * 16 + c][k0];
#pragma unroll
    for (int i = 0; i < 9; i++) b[i] = *(const bf8*)(wt + rowb[i] + k0);
#pragma unroll
    for (int mt = 0; mt < 4; mt++)
#pragma unroll
      for (int i = 0; i < 9; i++)
        acc[mt][i] = __builtin_amdgcn_mfma_f32_16x16x32_bf16(a[mt], b[i], acc[mt][i], 0, 0, 0);
  }
  __syncthreads();
  unsigned vpk[3][4][2];
#pragma unroll
  for (int i = 0; i < 9; i++) {
    const int kind = i / 3;
    const int col = (3 * w + i % 3) * 16 + c;
    const float bb = (kind == 0) ? (0.25f * L2E) * bq[col] : (kind == 1 ? bk[col] : bv[col]);
#pragma unroll
    for (int mt = 0; mt < 4; mt++) {
      unsigned w0 = pk2(acc[mt][i][0] + bb, acc[mt][i][1] + bb);
      unsigned w1 = pk2(acc[mt][i][2] + bb, acc[mt][i][3] + bb);
      if (kind == 2) {
        vpk[i - 6][mt][0] = w0;
        vpk[i - 6][mt][1] = w1;
      } else {
        short* dst = (kind == 0) ? &sm.u.qk.qs[0][0] : &sm.u.qk.ks[0][0];
        dst[(mt * 16 + g * 4 + 0) * 200 + col] = (short)(w0 & 0xFFFFu);
        dst[(mt * 16 + g * 4 + 1) * 200 + col] = (short)(w0 >> 16);
        dst[(mt * 16 + g * 4 + 2) * 200 + col] = (short)(w1 & 0xFFFFu);
        dst[(mt * 16 + g * 4 + 3) * 200 + col] = (short)(w1 >> 16);
      }
    }
  }
  const f4 z4 = {0.f, 0.f, 0.f, 0.f};
#pragma unroll
  for (int t = 0; t < 3; t++) {
    const int h  = 3 * w + t;
    const int hb = h * 16;
    bf4 afr[4], bfr[4];
#pragma unroll
    for (int nt = 0; nt < 4; nt++)
      afr[nt] = *(const bf4*)&sm.u.qk.ks[nt * 16 + c][hb + g * 4];
#pragma unroll
    for (int mt = 0; mt < 4; mt++)
      bfr[mt] = *(const bf4*)&sm.u.qk.qs[mt * 16 + c][hb + g * 4];
    f4 s[4][4];
#pragma unroll
    for (int nt = 0; nt < 4; nt++)
#pragma unroll
      for (int mt = 0; mt < 4; mt++)
        s[nt][mt] = mfma16(afr[nt], bfr[mt], z4);
    if (COMB) {
      const float* cbH = combF + cwin + (h << 12);
#pragma unroll
      for (int nt = 0; nt < 4; nt++)
#pragma unroll
        for (int r = 0; r < 4; r++) {
          const int n = nt * 16 + g * 4 + r;
          f4 cb4 = *(const f4*)&cbH[n * 64 + c * 4];
#pragma unroll
          for (int mt = 0; mt < 4; mt++)
            s[nt][mt][r] += cb4[mt];
        }
    } else {
      const float* bsH = biasF + (h << 12);
#pragma unroll
      for (int nt = 0; nt < 4; nt++)
#pragma unroll
        for (int r = 0; r < 4; r++) {
          const int n = nt * 16 + g * 4 + r;
          f4 b4 = *(const f4*)&bsH[n * 64 + c * 4];
          f4 m4 = *(const f4*)&maskF[mwin + n * 64 + c * 4];
#pragma unroll
          for (int mt = 0; mt < 4; mt++)
            s[nt][mt][r] += b4[mt] + m4[mt];
        }
    }
    float rin[4];
#pragma unroll
    for (int mt = 0; mt < 4; mt++) {
      float sum = 0.f;
#pragma unroll
      for (int nt = 0; nt < 4; nt++)
#pragma unroll
        for (int r = 0; r < 4; r++) {
          float p = ex2(s[nt][mt][r]);
          s[nt][mt][r] = p;
          sum += p;
        }
      sum += __shfl_xor(sum, 16, 64);
      sum += __shfl_xor(sum, 32, 64);
      rin[mt] = 1.f / sum;
    }
    unsigned ppk[4][4][2];
#pragma unroll
    for (int nt = 0; nt < 4; nt++)
#pragma unroll
      for (int mt = 0; mt < 4; mt++) {
        ppk[nt][mt][0] = pk2(s[nt][mt][0], s[nt][mt][1]);
        ppk[nt][mt][1] = pk2(s[nt][mt][2], s[nt][mt][3]);
      }
    f4 o[4];
#pragma unroll
    for (int mt = 0; mt < 4; mt++) o[mt] = z4;
#pragma unroll
    for (int kt = 0; kt < 4; kt++) {
      VU vu; vu.u[0] = vpk[t][kt][0]; vu.u[1] = vpk[t][kt][1];
#pragma unroll
      for (int mt = 0; mt < 4; mt++) {
        VU pu; pu.u[0] = ppk[kt][mt][0]; pu.u[1] = ppk[kt][mt][1];
        o[mt] = mfma16(vu.v, pu.v, o[mt]);
      }
    }
#pragma unroll
    for (int mt = 0; mt < 4; mt++) {
      f4 ov = o[mt] * rin[mt];
      *(bf4*)&sm.u.qk.qs[mt * 16 + c][hb + g * 4] = pkbf4(ov);
    }
  }
  bf8 wb0[6];
#pragma unroll
  for (int jt = 0; jt < 6; jt++)
    wb0[jt] = *(const bf8*)(wpt + (w * 96 + jt * 16 + c) * 192 + g * 8);
  __syncthreads();
  f4 acc3[6][4];
#pragma unroll
  for (int jt = 0; jt < 6; jt++)
#pragma unroll
    for (int mt = 0; mt < 4; mt++) acc3[jt][mt] = z4;
  {
    const int k0 = g * 8;
    bf8 ao[4];
#pragma unroll
    for (int mt = 0; mt < 4; mt++) ao[mt] = *(const bf8*)&sm.u.qk.qs[mt * 16 + c][k0];
#pragma unroll
    for (int jt = 0; jt < 6; jt++)
#pragma unroll
      for (int mt = 0; mt < 4; mt++)
        acc3[jt][mt] = __builtin_amdgcn_mfma_f32_16x16x32_bf16(wb0[jt], ao[mt], acc3[jt][mt], 0, 0, 0);
  }
#pragma unroll 2
  for (int ks3 = 1; ks3 < 6; ks3++) {
    const int k0 = ks3 * 32 + g * 8;
    bf8 ao[4], wbr[6];
#pragma unroll
    for (int mt = 0; mt < 4; mt++) ao[mt] = *(const bf8*)&sm.u.qk.qs[mt * 16 + c][k0];
#pragma unroll
    for (int jt = 0; jt < 6; jt++)
      wbr[jt] = *(const bf8*)(wpt + (w * 96 + jt * 16 + c) * 192 + k0);
#pragma unroll
    for (int jt = 0; jt < 6; jt++)
#pragma unroll
      for (int mt = 0; mt < 4; mt++)
        acc3[jt][mt] = __builtin_amdgcn_mfma_f32_16x16x32_bf16(wbr[jt], ao[mt], acc3[jt][mt], 0, 0, 0);
  }
  float* ow = out + (size_t)blk * 18816;
#pragma unroll
  for (int jt = 0; jt < 6; jt++) {
    const int colb = w * 96 + jt * 16 + g * 4;
    const f4 bp4 = *(const f4*)&bp[colb];
#pragma unroll
    for (int mt = 0; mt < 4; mt++) {
      const int m = mt * 16 + c;
      if (m < 49) {
        f4 v = acc3[jt][mt] + bp4;
        *(f4*)&ow[m * 384 + colb] = v;
      }
    }
  }
}

extern "C" void kernel_launch(void* const* d_in, const int* in_sizes, int n_in,
                              void* d_out, int out_size, void* d_ws, size_t ws_size,
                              hipStream_t stream) {
  const float* x    = (const float*)d_in[0];
  const float* mask = (const float*)d_in[1];
  const float* Wq   = (const float*)d_in[2];
  const float* bq   = (const float*)d_in[3];
  const float* Wk   = (const float*)d_in[4];
  const float* bk   = (const float*)d_in[5];
  const float* Wv   = (const float*)d_in[6];
  const float* bv   = (const float*)d_in[7];
  const float* Wp   = (const float*)d_in[8];
  const float* bp   = (const float*)d_in[9];
  const float* btab = (const float*)d_in[10];
  const int*   ridx = (const int*)d_in[11];
  float* out = (float*)d_out;

  char* ws = (char*)d_ws;
  short* wt    = (short*)ws;                    // [0, 442368)
  short* wpt   = (short*)(ws + 442368);         // [.., 589824)
  float* biasF = (float*)(ws + 589824);
  float* maskF = (float*)(ws + 786432);
  float* combF = (float*)(ws + 589824);         // [.., 13172736) when comb
  short* qtg   = (short*)(ws + 13172736);       // [.., 63504384)
  short* ktg   = (short*)(ws + 63504384);       // [.., 113836032)
  short* vtg   = (short*)(ws + 113836032);      // [.., 164167680)

  const size_t NEED_COMB  = 13172736u;
  const size_t NEED_SPLIT = 164167680u;

  if (ws_size >= NEED_SPLIT) {
    const int NPREP = 576 * 384 + 384 * 192 + 64 * 12 * 64 * 64;
    wa_prep<<<dim3((NPREP + 255) / 256), dim3(256), 0, stream>>>(
        Wq, Wk, Wv, Wp, btab, ridx, mask, 1, wt, wpt, biasF, maskF, combF);
    wa_qkv<<<dim3(2048), dim3(256), 0, stream>>>(x, bq, bk, bv, wt, qtg, ktg, vtg);
    wa_attn<<<dim3(2048), dim3(256), 0, stream>>>(qtg, ktg, vtg, wpt, combF, bp, out);
  } else if (ws_size >= NEED_COMB) {
    const int NPREP = 576 * 384 + 384 * 192 + 64 * 12 * 64 * 64;
    wa_prep<<<dim3((NPREP + 255) / 256), dim3(256), 0, stream>>>(
        Wq, Wk, Wv, Wp, btab, ridx, mask, 1, wt, wpt, biasF, maskF, combF);
    wa_main<true><<<dim3(2048), dim3(256), 0, stream>>>(
        x, bq, bk, bv, bp, wt, wpt, biasF, maskF, combF, out);
  } else {
    const int NPREP = 576 * 384 + 384 * 192 + 12 * 64 * 64 + 64 * 64 * 64;
    wa_prep<<<dim3((NPREP + 255) / 256), dim3(256), 0, stream>>>(
        Wq, Wk, Wv, Wp, btab, ridx, mask, 0, wt, wpt, biasF, maskF, combF);
    wa_main<false><<<dim3(2048), dim3(256), 0, stream>>>(
        x, bq, bk, bv, bp, wt, wpt, biasF, maskF, combF, out);
  }
}

// Round 24
// 216.296 us; speedup vs baseline: 1.2771x; 1.2771x over previous
//
#include <hip/hip_runtime.h>
#include <hip/hip_bf16.h>

// Swin WindowAttention, fully fused: one window (49 tokens) per 256-thread block.
// FINAL (R24 = R22 champion, 216.5us): K=16 attention MFMAs, in-lane PV via vpk
// regs, exp2-domain softmax without max-pass, deferred 1/sum, combined bias+mask
// f32 table (L2-resident), fence-free phase 2, 2 blocks/CU.
// Session findings baked in:
//  - occupancy is register-file-capped at 2 waves/SIMD: phase-1's acc[4][9]
//    (144 f32) + ~116 arch regs ~= the 256/wave budget; every push (squeeze,
//    six-pass diet, 512-thr work-split, kernel split) spilled or serialized
//    (R3/R10/R11/R16/R18/R23). R23 proved the fused kernel already overlaps
//    QKV/attention phases across the 2 co-resident blocks (A alone = 80% of
//    fused total).
//  - chain cuts that shipped: K=16 PV with zero cross-lane movement (R12,
//    -240 bpermutes), exp2 softmax (R14), no max-pass (R19, -24 serialized
//    shuffles/wave), combined table (R21).
//  - known-null: I$ code-size (R15/R16), setprio (R20), fences (R22),
//    cvt_pk inline-asm is WRONG on gfx950 (R13, absmax 3.2).

typedef __attribute__((ext_vector_type(8))) short  bf8;   // MFMA A/B frag, K=32 GEMMs
typedef __attribute__((ext_vector_type(4))) short  bf4;   // MFMA A/B frag, K=16 + 8B ld/st
typedef __attribute__((ext_vector_type(4))) float  f4;    // MFMA C/D frag

#define L2E 1.4426950408889634f

union VU { unsigned u[2]; bf4 v; };

__device__ __forceinline__ short f2b(float f) {           // f32 -> bf16 bits, RNE (prep)
  unsigned u = __builtin_bit_cast(unsigned, f);
  unsigned r = u + 0x7fffu + ((u >> 16) & 1u);
  return (short)(r >> 16);
}
__device__ __forceinline__ unsigned pk2(float lo, float hi) { // 2xf32 -> packed bf16
  unsigned short l = __builtin_bit_cast(unsigned short, __float2bfloat16(lo));
  unsigned short h = __builtin_bit_cast(unsigned short, __float2bfloat16(hi));
  return (unsigned)l | ((unsigned)h << 16);
}
__device__ __forceinline__ bf4 pkbf4(f4 v) {
  VU r; r.u[0] = pk2(v[0], v[1]); r.u[1] = pk2(v[2], v[3]);
  return r.v;
}
__device__ __forceinline__ float ex2(float x) {           // 2^x (softmax pre-scaled)
#if __has_builtin(__builtin_amdgcn_exp2f)
  return __builtin_amdgcn_exp2f(x);
#else
  float r; asm("v_exp_f32 %0, %1" : "=v"(r) : "v"(x)); return r;
#endif
}
__device__ __forceinline__ f4 mfma16(bf4 a, bf4 b, f4 c) {
#if __has_builtin(__builtin_amdgcn_mfma_f32_16x16x16bf16_1k)
  return __builtin_amdgcn_mfma_f32_16x16x16bf16_1k(a, b, c, 0, 0, 0);
#else
  f4 d;
  asm("v_mfma_f32_16x16x16_bf16 %0, %1, %2, %3" : "=v"(d) : "v"(a), "v"(b), "v"(c));
  return d;
#endif
}

// ---- prep: Wt[576][384] bf16 (q rows pre-scaled 0.25*log2e), Wpt[384][192] bf16,
// then EITHER combF[64][12][64][64] f32 (comb=1)
//      OR     biasF[12][64][64] + maskF[64][64][64] f32 (comb=0 fallback).
// Swizzled lane layout [..][n][c*4+mt]; pad rows n>=49 = -14427 (log2 domain).
__global__ void wa_prep(const float* __restrict__ Wq, const float* __restrict__ Wk,
                        const float* __restrict__ Wv, const float* __restrict__ Wp,
                        const float* __restrict__ btab, const int* __restrict__ ridx,
                        const float* __restrict__ mask, int comb,
                        short* __restrict__ wt, short* __restrict__ wpt,
                        float* __restrict__ biasF, float* __restrict__ maskF,
                        float* __restrict__ combF) {
  int id = blockIdx.x * 256 + threadIdx.x;
  const int NWT = 576 * 384, NWP = 384 * 192;
  const int NBS = 12 * 64 * 64, NMS = 64 * 64 * 64, NCB = 64 * 12 * 64 * 64;
  if (id < NWT) {
    int row = id / 384, k = id - row * 384;
    int kind = row / 192, cc = row - kind * 192;
    const float* W = (kind == 0) ? Wq : (kind == 1 ? Wk : Wv);
    float v = W[k * 192 + cc];
    if (kind == 0) v *= 0.25f * L2E;            // fold attn scale AND log2e into Q
    wt[id] = f2b(v);
    return;
  }
  id -= NWT;
  if (id < NWP) {
    int n = id / 192, k = id - n * 192;
    wpt[id] = f2b(Wp[k * 384 + n]);
    return;
  }
  id -= NWP;
  if (comb) {
    if (id < NCB) {
      int win = id / 49152, rem = id - win * 49152;
      int h = rem >> 12, r2 = rem & 4095;
      int n = r2 >> 6, cc = r2 & 63;
      int m = (cc & 3) * 16 + (cc >> 2);        // m = mt*16 + c
      float v;
      if (n >= 49)      v = -14427.0f;
      else if (m >= 49) v = 0.0f;
      else              v = (btab[ridx[m * 49 + n] * 12 + h]
                             + mask[win * 2401 + m * 49 + n]) * L2E;
      combF[id] = v;
    }
  } else {
    if (id < NBS) {
      int h = id >> 12, rem = id & 4095;
      int n = rem >> 6, cc = rem & 63;
      int m = (cc & 3) * 16 + (cc >> 2);
      float v;
      if (n >= 49)      v = -14427.0f;
      else if (m >= 49) v = 0.0f;
      else              v = btab[ridx[m * 49 + n] * 12 + h] * L2E;
      biasF[id] = v;
    } else if ((id -= NBS) < NMS) {
      int win = id >> 12, rem = id & 4095;
      int n = rem >> 6, cc = rem & 63;
      int m = (cc & 3) * 16 + (cc >> 2);
      maskF[id] = (m < 49 && n < 49) ? mask[win * 2401 + m * 49 + n] * L2E : 0.f;
    }
  }
}

struct __align__(16) Smem {
  union U {
    short xs[64][392];                                      // 50176 B (staging/phase 1)
    struct QK { short qs[64][200]; short ks[64][200]; } qk; // 51200 B (qs doubles as O)
  } u;
};                                                          // 51200 B

template <bool COMB>
__global__ __launch_bounds__(256, 2)
void wa_main(const float* __restrict__ x,
             const float* __restrict__ bq, const float* __restrict__ bk,
             const float* __restrict__ bv, const float* __restrict__ bp,
             const short* __restrict__ wt, const short* __restrict__ wpt,
             const float* __restrict__ biasF, const float* __restrict__ maskF,
             const float* __restrict__ combF, float* __restrict__ out) {
  __shared__ Smem sm;
  const int tid = threadIdx.x;
  const int w   = tid >> 6;          // wave 0..3, owns heads 3w..3w+2
  const int lid = tid & 63;
  const int g   = lid >> 4;          // quad-group 0..3
  const int c   = lid & 15;          // lane-in-group
  const int blk = blockIdx.x;
  const int mwin = (blk & 63) << 12;        // maskF window base (separate path)
  const int cwin = (blk & 63) * 49152;      // combF window base (combined path)

  // ---- stage x -> bf16 LDS (batched loads), zero-pad token rows 49..63 ----
  {
    const float* xw = x + (size_t)blk * 18816;
    f4 xv[18];
#pragma unroll
    for (int it = 0; it < 18; it++) {
      int i = tid + it * 256;
      xv[it] = *(const f4*)(xw + (i / 96) * 384 + (i % 96) * 4);
    }
    const int iT = tid + 18 * 256;
    f4 xt = {0.f, 0.f, 0.f, 0.f};
    if (iT < 4704) xt = *(const f4*)(xw + (iT / 96) * 384 + (iT % 96) * 4);
#pragma unroll
    for (int it = 0; it < 18; it++) {
      int i = tid + it * 256;
      *(bf4*)&sm.u.xs[i / 96][(i % 96) * 4] = pkbf4(xv[it]);
    }
    if (iT < 4704) *(bf4*)&sm.u.xs[iT / 96][(iT % 96) * 4] = pkbf4(xt);
    const bf8 zz = {0,0,0,0,0,0,0,0};
#pragma unroll
    for (int it = 0; it < 3; it++) {
      int i = tid + it * 256;
      if (i < 735) { int row = 49 + i / 49, c8 = (i % 49) * 8; *(bf8*)&sm.u.xs[row][c8] = zz; }
    }
  }
  __syncthreads();

  // ---- phase 1: QKV = x @ [Wq|Wk|Wv]; wave w -> q,k,v of heads 3w..3w+2 ----
  f4 acc[4][9];
#pragma unroll
  for (int mt = 0; mt < 4; mt++)
#pragma unroll
    for (int i = 0; i < 9; i++) acc[mt][i] = (f4){0.f, 0.f, 0.f, 0.f};
  int rowb[9];
#pragma unroll
  for (int i = 0; i < 9; i++) {
    int kind = i / 3, hh = 3 * w + i % 3;
    rowb[i] = (kind * 192 + hh * 16 + c) * 384;
  }
#pragma unroll 3
  for (int ks = 0; ks < 12; ks++) {
    const int k0 = ks * 32 + g * 8;
    bf8 a[4], b[9];
#pragma unroll
    for (int mt = 0; mt < 4; mt++) a[mt] = *(const bf8*)&sm.u.xs[mt * 16 + c][k0];
#pragma unroll
    for (int i = 0; i < 9; i++) b[i] = *(const bf8*)(wt + rowb[i] + k0);
#pragma unroll
    for (int mt = 0; mt < 4; mt++)
#pragma unroll
      for (int i = 0; i < 9; i++)
        acc[mt][i] = __builtin_amdgcn_mfma_f32_16x16x32_bf16(a[mt], b[i], acc[mt][i], 0, 0, 0);
  }
  __syncthreads();   // xs reads done; region becomes qs/ks

  // ---- Q,K -> LDS row-major; V -> registers packed bf16 ----
  unsigned vpk[3][4][2];   // [head][mt][rp]: tokens (mt*16+g*4+2rp, +1), dim hb+c
#pragma unroll
  for (int i = 0; i < 9; i++) {
    const int kind = i / 3;
    const int col = (3 * w + i % 3) * 16 + c;
    const float bb = (kind == 0) ? (0.25f * L2E) * bq[col] : (kind == 1 ? bk[col] : bv[col]);
#pragma unroll
    for (int mt = 0; mt < 4; mt++) {
      unsigned w0 = pk2(acc[mt][i][0] + bb, acc[mt][i][1] + bb);
      unsigned w1 = pk2(acc[mt][i][2] + bb, acc[mt][i][3] + bb);
      if (kind == 2) {
        vpk[i - 6][mt][0] = w0;
        vpk[i - 6][mt][1] = w1;
      } else {
        short* dst = (kind == 0) ? &sm.u.qk.qs[0][0] : &sm.u.qk.ks[0][0];
        dst[(mt * 16 + g * 4 + 0) * 200 + col] = (short)(w0 & 0xFFFFu);
        dst[(mt * 16 + g * 4 + 1) * 200 + col] = (short)(w0 >> 16);
        dst[(mt * 16 + g * 4 + 2) * 200 + col] = (short)(w1 & 0xFFFFu);
        dst[(mt * 16 + g * 4 + 3) * 200 + col] = (short)(w1 >> 16);
      }
    }
  }
  // (no fence: same-wave qs/ks write->read pairs are program-ordered; scheduler
  // free to overlap provably-disjoint ops.)

  // ---- phase 2: per-head attention, S^T = K*Q^T then O^T = V^T*P^T (all K=16) ----
  const f4 z4 = {0.f, 0.f, 0.f, 0.f};
#pragma unroll
  for (int t = 0; t < 3; t++) {
    const int h  = 3 * w + t;
    const int hb = h * 16;
    bf4 afr[4], bfr[4];                         // K=16 frags: 8B LDS reads
#pragma unroll
    for (int nt = 0; nt < 4; nt++)
      afr[nt] = *(const bf4*)&sm.u.qk.ks[nt * 16 + c][hb + g * 4];
#pragma unroll
    for (int mt = 0; mt < 4; mt++)
      bfr[mt] = *(const bf4*)&sm.u.qk.qs[mt * 16 + c][hb + g * 4];
    f4 s[4][4];                                 // S^T[n = nt*16+g*4+r][m = mt*16+c], log2-scaled
#pragma unroll
    for (int nt = 0; nt < 4; nt++)
#pragma unroll
      for (int mt = 0; mt < 4; mt++)
        s[nt][mt] = mfma16(afr[nt], bfr[mt], z4);
    // bias + mask, pre-scaled by log2e
    if (COMB) {
      const float* cbH = combF + cwin + (h << 12);   // one f4 load per (nt,r)
#pragma unroll
      for (int nt = 0; nt < 4; nt++)
#pragma unroll
        for (int r = 0; r < 4; r++) {
          const int n = nt * 16 + g * 4 + r;
          f4 cb4 = *(const f4*)&cbH[n * 64 + c * 4];
#pragma unroll
          for (int mt = 0; mt < 4; mt++)
            s[nt][mt][r] += cb4[mt];
        }
    } else {
      const float* bsH = biasF + (h << 12);
#pragma unroll
      for (int nt = 0; nt < 4; nt++)
#pragma unroll
        for (int r = 0; r < 4; r++) {
          const int n = nt * 16 + g * 4 + r;
          f4 b4 = *(const f4*)&bsH[n * 64 + c * 4];
          f4 m4 = *(const f4*)&maskF[mwin + n * 64 + c * 4];
#pragma unroll
          for (int mt = 0; mt < 4; mt++)
            s[nt][mt][r] += b4[mt] + m4[mt];
        }
    }
    // softmax over n per column m: NO max-pass (exp2 domain, |s| bounded <<127);
    // un-normalized p, sum + deferred 1/sum. bf16 is scale-invariant.
    float rin[4];
#pragma unroll
    for (int mt = 0; mt < 4; mt++) {
      float sum = 0.f;
#pragma unroll
      for (int nt = 0; nt < 4; nt++)
#pragma unroll
        for (int r = 0; r < 4; r++) {
          float p = ex2(s[nt][mt][r]);
          s[nt][mt][r] = p;
          sum += p;
        }
      sum += __shfl_xor(sum, 16, 64);
      sum += __shfl_xor(sum, 32, 64);
      rin[mt] = 1.f / sum;
    }
    // pack un-normalized P^T to bf16 pairs: ppk[kt][mt][rp] (in-lane PV B-frags)
    unsigned ppk[4][4][2];
#pragma unroll
    for (int nt = 0; nt < 4; nt++)
#pragma unroll
      for (int mt = 0; mt < 4; mt++) {
        ppk[nt][mt][0] = pk2(s[nt][mt][0], s[nt][mt][1]);
        ppk[nt][mt][1] = pk2(s[nt][mt][2], s[nt][mt][3]);
      }
    // O^T = V^T @ P^T: 4 x K=16 sub-MFMAs; A = vpk[t][kt], B = ppk[kt][mt], in-lane.
    f4 o[4];
#pragma unroll
    for (int mt = 0; mt < 4; mt++) o[mt] = z4;
#pragma unroll
    for (int kt = 0; kt < 4; kt++) {
      VU vu; vu.u[0] = vpk[t][kt][0]; vu.u[1] = vpk[t][kt][1];
#pragma unroll
      for (int mt = 0; mt < 4; mt++) {
        VU pu; pu.u[0] = ppk[kt][mt][0]; pu.u[1] = ppk[kt][mt][1];
        o[mt] = mfma16(vu.v, pu.v, o[mt]);
      }
    }
    // deferred softmax normalization (per token m = mt*16+c), then pack + store O^T
    // (O columns = this head only; disjoint from later heads' Q reads — no fence)
#pragma unroll
    for (int mt = 0; mt < 4; mt++) {
      f4 ov = o[mt] * rin[mt];
      *(bf4*)&sm.u.qk.qs[mt * 16 + c][hb + g * 4] = pkbf4(ov);
    }
  }

  // hoist phase-3 ks3=0 weight frags above the barrier (independent of LDS)
  bf8 wb0[6];
#pragma unroll
  for (int jt = 0; jt < 6; jt++)
    wb0[jt] = *(const bf8*)(wpt + (w * 96 + jt * 16 + c) * 192 + g * 8);
  __syncthreads();   // all heads' O visible to all waves

  // ---- phase 3: out^T = Wp^T @ O^T (vectorized f4 epilogue) ----
  f4 acc3[6][4];
#pragma unroll
  for (int jt = 0; jt < 6; jt++)
#pragma unroll
    for (int mt = 0; mt < 4; mt++) acc3[jt][mt] = z4;
  {                                            // peeled ks3 = 0 (uses wb0)
    const int k0 = g * 8;
    bf8 ao[4];
#pragma unroll
    for (int mt = 0; mt < 4; mt++) ao[mt] = *(const bf8*)&sm.u.qk.qs[mt * 16 + c][k0];
#pragma unroll
    for (int jt = 0; jt < 6; jt++)
#pragma unroll
      for (int mt = 0; mt < 4; mt++)
        acc3[jt][mt] = __builtin_amdgcn_mfma_f32_16x16x32_bf16(wb0[jt], ao[mt], acc3[jt][mt], 0, 0, 0);
  }
#pragma unroll 2
  for (int ks3 = 1; ks3 < 6; ks3++) {
    const int k0 = ks3 * 32 + g * 8;
    bf8 ao[4], wb[6];
#pragma unroll
    for (int mt = 0; mt < 4; mt++) ao[mt] = *(const bf8*)&sm.u.qk.qs[mt * 16 + c][k0];
#pragma unroll
    for (int jt = 0; jt < 6; jt++)
      wb[jt] = *(const bf8*)(wpt + (w * 96 + jt * 16 + c) * 192 + k0);
#pragma unroll
    for (int jt = 0; jt < 6; jt++)
#pragma unroll
      for (int mt = 0; mt < 4; mt++)
        acc3[jt][mt] = __builtin_amdgcn_mfma_f32_16x16x32_bf16(wb[jt], ao[mt], acc3[jt][mt], 0, 0, 0);
  }
  float* ow = out + (size_t)blk * 18816;
#pragma unroll
  for (int jt = 0; jt < 6; jt++) {
    const int colb = w * 96 + jt * 16 + g * 4;
    const f4 bp4 = *(const f4*)&bp[colb];
#pragma unroll
    for (int mt = 0; mt < 4; mt++) {
      const int m = mt * 16 + c;
      if (m < 49) {
        f4 v = acc3[jt][mt] + bp4;
        *(f4*)&ow[m * 384 + colb] = v;
      }
    }
  }
}

extern "C" void kernel_launch(void* const* d_in, const int* in_sizes, int n_in,
                              void* d_out, int out_size, void* d_ws, size_t ws_size,
                              hipStream_t stream) {
  const float* x    = (const float*)d_in[0];
  const float* mask = (const float*)d_in[1];
  const float* Wq   = (const float*)d_in[2];
  const float* bq   = (const float*)d_in[3];
  const float* Wk   = (const float*)d_in[4];
  const float* bk   = (const float*)d_in[5];
  const float* Wv   = (const float*)d_in[6];
  const float* bv   = (const float*)d_in[7];
  const float* Wp   = (const float*)d_in[8];
  const float* bp   = (const float*)d_in[9];
  const float* btab = (const float*)d_in[10];
  const int*   ridx = (const int*)d_in[11];
  float* out = (float*)d_out;

  char* ws = (char*)d_ws;
  short* wt    = (short*)ws;                    // [0, 442368)    Wt bf16
  short* wpt   = (short*)(ws + 442368);         // [.., 589824)   Wpt bf16
  // combined layout: combF f32 [64][12][64][64] at 589824 (ends 13172736)
  // separate layout: biasF at 589824 (196608 B), maskF at 786432 (1048576 B)
  float* biasF = (float*)(ws + 589824);
  float* maskF = (float*)(ws + 786432);
  float* combF = (float*)(ws + 589824);

  const size_t NEED_COMB = 589824u + 64u * 12u * 64u * 64u * 4u;   // 13172736
  const int comb = (ws_size >= NEED_COMB) ? 1 : 0;

  if (comb) {
    const int NPREP = 576 * 384 + 384 * 192 + 64 * 12 * 64 * 64;   // 3440640
    wa_prep<<<dim3((NPREP + 255) / 256), dim3(256), 0, stream>>>(
        Wq, Wk, Wv, Wp, btab, ridx, mask, 1, wt, wpt, biasF, maskF, combF);
    wa_main<true><<<dim3(2048), dim3(256), 0, stream>>>(
        x, bq, bk, bv, bp, wt, wpt, biasF, maskF, combF, out);
  } else {
    const int NPREP = 576 * 384 + 384 * 192 + 12 * 64 * 64 + 64 * 64 * 64;
    wa_prep<<<dim3((NPREP + 255) / 256), dim3(256), 0, stream>>>(
        Wq, Wk, Wv, Wp, btab, ridx, mask, 0, wt, wpt, biasF, maskF, combF);
    wa_main<false><<<dim3(2048), dim3(256), 0, stream>>>(
        x, bq, bk, bv, bp, wt, wpt, biasF, maskF, combF, out);
  }
}